// Round 1
// baseline (187.389 us; speedup 1.0000x reference)
//
#include <hip/hip_runtime.h>
#include <stdint.h>

// Problem constants (from reference): inputs (4, 200, 64, 64, 8) fp32
#define BDIM    4
#define TTOT    200
#define CHUNK   100
#define HWC     32768          // 64*64*8
#define NEUR    (BDIM * HWC)   // 131072 neurons
#define REGION_BYTES (HWC * 4) // 131072 bytes of output per (b,t)

// Kernel 1: integrate-and-fire scan per (neuron, chunk).
// Writes spikes as uint8 into the first 32 KB of each (b,t) output region.
// Reads coalesced: at fixed t, lanes read consecutive floats.
__global__ __launch_bounds__(256) void spike_kernel(const float* __restrict__ x,
                                                    uint8_t* __restrict__ out8) {
    unsigned g     = blockIdx.x * 256u + threadIdx.x;  // [0, 262144)
    unsigned n     = g & (NEUR - 1);                   // neuron id
    unsigned chunk = g >> 17;                          // 0 or 1
    unsigned b     = n >> 15;                          // n / HWC
    unsigned i     = n & (HWC - 1);
    unsigned t0    = b * TTOT + chunk * CHUNK;         // (b, ct) region base index

    const float* xp = x    + (size_t)t0 * HWC + i;
    uint8_t*     sp = out8 + (size_t)t0 * REGION_BYTES + i;

    float acc = 0.0f;
#pragma unroll 4
    for (int t = 0; t < CHUNK; ++t) {
        float v = xp[(size_t)t * HWC];
        acc += v;                       // sequential fp32 == np.cumsum order
        uint8_t s = 0;
        if (acc > 2.0f) { s = 1; acc = 0.0f; }  // strict >, full reset
        sp[(size_t)t * REGION_BYTES] = s;
    }
}

// Kernel 2: per (b,t) block, transpose 64x512 uint8 (h, w*c) -> 512x64 fp32 (w*c, h)
// through LDS. In-place over d_out regions: reads only this block's 32 KB
// (written by kernel 1), then overwrites the full 128 KB region.
__global__ __launch_bounds__(256) void transpose_kernel(float* __restrict__ out) {
    __shared__ uint32_t lds32[64 * 129];  // row stride 129 u32 = 516 B (pad +4B: bank-conflict-free)
    unsigned blk = blockIdx.x;            // (b*200 + t), 800 blocks
    unsigned tid = threadIdx.x;

    const uint32_t* in32 = (const uint32_t*)((const uint8_t*)out + (size_t)blk * REGION_BYTES);

#pragma unroll 8
    for (int it = 0; it < 32; ++it) {
        unsigned idx = it * 256u + tid;   // u32 index in [0, 8192)
        unsigned h   = idx >> 7;          // 128 u32 per row
        unsigned wq  = idx & 127u;
        lds32[h * 129u + wq] = in32[idx]; // coalesced global read, conflict-free LDS write
    }
    __syncthreads();

    const uint8_t* lds8 = (const uint8_t*)lds32;
    float4* out4 = (float4*)out + (size_t)blk * 8192u;

#pragma unroll 8
    for (int it = 0; it < 32; ++it) {
        unsigned o4   = it * 256u + tid;  // float4 index in [0, 8192)
        unsigned oidx = o4 * 4u;          // element index = wc*64 + h
        unsigned wc   = oidx >> 6;
        unsigned h0   = oidx & 63u;       // multiple of 4
        float4 v;
        v.x = (float)lds8[(h0 + 0u) * 516u + wc];
        v.y = (float)lds8[(h0 + 1u) * 516u + wc];
        v.z = (float)lds8[(h0 + 2u) * 516u + wc];
        v.w = (float)lds8[(h0 + 3u) * 516u + wc];
        out4[o4] = v;                     // coalesced 16B/lane store
    }
}

extern "C" void kernel_launch(void* const* d_in, const int* in_sizes, int n_in,
                              void* d_out, int out_size, void* d_ws, size_t ws_size,
                              hipStream_t stream) {
    (void)in_sizes; (void)n_in; (void)d_ws; (void)ws_size; (void)out_size;
    const float* x = (const float*)d_in[0];
    float* out = (float*)d_out;

    // K1: 262144 threads = 1024 blocks x 256 (neuron x chunk)
    hipLaunchKernelGGL(spike_kernel, dim3(NEUR * 2 / 256), dim3(256), 0, stream,
                       x, (uint8_t*)out);
    // K2: one block per (b,t) region
    hipLaunchKernelGGL(transpose_kernel, dim3(BDIM * TTOT), dim3(256), 0, stream,
                       out);
}